// Round 6
// baseline (165.911 us; speedup 1.0000x reference)
//
#include <hip/hip_runtime.h>
#include <hip/hip_bf16.h>
#include <stdint.h>
#include <stddef.h>

// MDCT as folded GEMM, fold fused into GEMM B-staging, XCD-swizzled grid,
// round 6: double-buffered BK=32 K-loop with one barrier per iteration and
// next-tile loads issued a full MFMA-phase before their use (restructured
// K-loop per the m97-plateau analysis — loads in flight across the barrier).
//   out[512, 32784] = D[512,512] . V[512, 32784]
//   V[c][j] = j<256:  x[g+j] - x[g+511-j]
//             j>=256: x[g+j+256] + x[g+1279-j],   g = o*512 - 512 (per batch)
// Precision: single fp16 product; absmax 0.03125 vs threshold 0.1069 (3.4x).
// Traffic verified optimal in r5: FETCH 62 MB + WRITE 74 MB = fused floor.

constexpr int N_ = 512;
constexpr int T_ = 2048;
constexpr int B_ = 16;
constexpr int LEN = N_ * T_;              // 2^20 per batch
constexpr int FRAMES = T_ + 1;            // 2049
constexpr int COLS = B_ * FRAMES;         // 32784
constexpr int NT_TILES = 257;
constexpr int KF = 512;
constexpr int BK = 32;
constexpr int KI = KF / BK;               // 16 k-iterations

typedef __attribute__((ext_vector_type(8))) _Float16 f16x8;
typedef __attribute__((ext_vector_type(4))) _Float16 f16x4;
typedef __attribute__((ext_vector_type(4))) float f32x4;

#define GLD16(gptr, lptr)                                                     \
  __builtin_amdgcn_global_load_lds(                                           \
      (const __attribute__((address_space(1))) unsigned int*)(gptr),          \
      (__attribute__((address_space(3))) unsigned int*)(lptr), 16, 0, 0)

// ---------------- Kernel 1: gather filter -> fp16 D -------------------------
__global__ void prep_filter(const float* __restrict__ f,
                            _Float16* __restrict__ D) {
  int idx = (blockIdx.x * 256 + threadIdx.x) * 4;
  int k = idx >> 9;
  int j = idx & 511;
  int t = (j < 256) ? j : (j + 256);
  const float4 v = *(const float4*)&f[k * 1024 + t];
  f16x4 h = {(_Float16)v.x, (_Float16)v.y, (_Float16)v.z, (_Float16)v.w};
  *(f16x4*)&D[k * KF + j] = h;
}

// ---------------- Kernel 2: fused fold + GEMM, dbuf pipeline ----------------
// 128x128 tile, BK=32 double-buffered, 4 waves (2x2 of 64x64), 16x16x32 f16.
// LDS slot map (both A and B): slot(row, chunk) = row*4 + (chunk ^ (row&3)),
// 16B chunks -> fragment reads are 2-way-bank-aliased (free, m136).
// Grid: id -> xcd=id&7, s=id>>3, m-tile=s&3, n-tile=(s>>2)*8+xcd (same-n
// blocks on one XCD; r5 verified FETCH 263->62 MB). Grid 1056, tail exits.
__global__ __launch_bounds__(256, 3) void gemm_fused(
    const _Float16* __restrict__ D, const float* __restrict__ x,
    float* __restrict__ out) {
  __shared__ __align__(16) _Float16 As[2][128 * BK];
  __shared__ __align__(16) _Float16 Bs[2][128 * BK];

  const int id = blockIdx.x;
  const int xcd = id & 7;
  const int sb = id >> 3;
  const int nt = (sb >> 2) * 8 + xcd;
  if (nt >= NT_TILES) return;        // block-uniform exit
  const int m0 = (sb & 3) * 128;
  const int n0 = nt * 128;

  const int tid = threadIdx.x;
  const int wid = tid >> 6;
  const int lane = tid & 63;
  const int quad = lane >> 4;
  const int l16 = lane & 15;
  const int mw = (wid >> 1) * 64;
  const int nw = (wid & 1) * 64;

  // B-staging ids: thread handles (row rh+u*64, chunk cch), chunk = 8 k.
  const int cch = tid & 3;
  const int rh = tid >> 2;             // 0..63
  int gg[2], lo2[2], slotB[2];
  bool ok2[2];
#pragma unroll
  for (int u = 0; u < 2; ++u) {
    int row = rh + u * 64;
    int col = n0 + row;
    int b = (int)((unsigned)col / (unsigned)FRAMES);
    int o = col - b * FRAMES;
    gg[u] = b * LEN + o * N_ - N_;     // window start (may be -512)
    lo2[u] = b * LEN;
    ok2[u] = (col < COLS);
    slotB[u] = row * 4 + (cch ^ (row & 3));
  }

  const _Float16* Dm = D + (size_t)m0 * KF;

  f32x4 acc[4][4];
#pragma unroll
  for (int i = 0; i < 4; ++i)
#pragma unroll
    for (int j = 0; j < 4; ++j) acc[i][j] = (f32x4){0.f, 0.f, 0.f, 0.f};

  float4 qa0[2], qa1[2], qr0[2], qr1[2];  // B prefetch registers

  auto stageA = [&](int kb, int buf) {
#pragma unroll
    for (int u2 = 0; u2 < 2; ++u2) {
      const int S = u2 * 256 + tid;        // slot id; LDS dest = base+lane*16
      const int rA = S >> 2;
      const int cA = (S & 3) ^ (rA & 3);   // swizzled global chunk
      GLD16(Dm + (size_t)rA * KF + kb + cA * 8, &As[buf][S * 8]);
    }
  };
  auto loadB = [&](int kb) {
    const bool mi = (kb < 256);
    const int j0 = kb + cch * 8;
    const int fo = mi ? j0 : (j0 + 256);           // fwd segment offset
    const int ro = mi ? (504 - j0) : (1272 - j0);  // rev segment offset
#pragma unroll
    for (int u = 0; u < 2; ++u) {
      qa0[u] = (float4){0.f, 0.f, 0.f, 0.f};
      qa1[u] = (float4){0.f, 0.f, 0.f, 0.f};
      qr0[u] = (float4){0.f, 0.f, 0.f, 0.f};
      qr1[u] = (float4){0.f, 0.f, 0.f, 0.f};
      if (ok2[u]) {
        const int fb = gg[u] + fo;
        const int rb2 = gg[u] + ro;
        if ((unsigned)(fb - lo2[u]) <= (unsigned)(LEN - 8)) {
          qa0[u] = *(const float4*)(x + fb);
          qa1[u] = *(const float4*)(x + fb + 4);
        }
        if ((unsigned)(rb2 - lo2[u]) <= (unsigned)(LEN - 8)) {
          qr0[u] = *(const float4*)(x + rb2);
          qr1[u] = *(const float4*)(x + rb2 + 4);
        }
      }
    }
  };
  auto writeB = [&](int kb, int buf) {
    const float sgn = (kb < 256) ? -1.0f : 1.0f;
#pragma unroll
    for (int u = 0; u < 2; ++u) {
      f16x8 h;
      h[0] = (_Float16)__builtin_fmaf(sgn, qr1[u].w, qa0[u].x);
      h[1] = (_Float16)__builtin_fmaf(sgn, qr1[u].z, qa0[u].y);
      h[2] = (_Float16)__builtin_fmaf(sgn, qr1[u].y, qa0[u].z);
      h[3] = (_Float16)__builtin_fmaf(sgn, qr1[u].x, qa0[u].w);
      h[4] = (_Float16)__builtin_fmaf(sgn, qr0[u].w, qa1[u].x);
      h[5] = (_Float16)__builtin_fmaf(sgn, qr0[u].z, qa1[u].y);
      h[6] = (_Float16)__builtin_fmaf(sgn, qr0[u].y, qa1[u].z);
      h[7] = (_Float16)__builtin_fmaf(sgn, qr0[u].x, qa1[u].w);
      *(f16x8*)&Bs[buf][slotB[u] * 8] = h;
    }
  };

  // Prologue: stage tile 0 into buffer 0 (cold-start latency, once).
  stageA(0, 0);
  loadB(0);
  writeB(0, 0);

  for (int kt = 0; kt < KI; ++kt) {
    const int cur = kt & 1;
    const int nxt = cur ^ 1;
    // Barrier: tile kt staged (vmcnt(0) drain covers A-DMA issued last iter;
    // lgkm covers ds_writes) AND all waves done reading buffer `nxt` (kt-1).
    __syncthreads();
    if (kt + 1 < KI) {
      const int kbn = (kt + 1) * BK;
      stageA(kbn, nxt);   // async DMA, lands by next barrier
      loadB(kbn);         // register loads, consumed after MFMA below
    }
    // Fragment reads + MFMA on current tile (hides the loads above).
    f16x8 af[4], bfr[4];
#pragma unroll
    for (int i = 0; i < 4; ++i) {
      const int ra = mw + i * 16 + l16;
      const int rb = nw + i * 16 + l16;
      af[i] = *(const f16x8*)&As[cur][(ra * 4 + (quad ^ (ra & 3))) * 8];
      bfr[i] = *(const f16x8*)&Bs[cur][(rb * 4 + (quad ^ (rb & 3))) * 8];
    }
#pragma unroll
    for (int i = 0; i < 4; ++i)
#pragma unroll
      for (int j = 0; j < 4; ++j)
        acc[i][j] = __builtin_amdgcn_mfma_f32_16x16x32_f16(af[i], bfr[j], acc[i][j], 0, 0, 0);
    // Fold + LDS write for tile kt+1 (B regs have had the MFMA phase to land).
    if (kt + 1 < KI) writeB((kt + 1) * BK, nxt);
  }

  // ---- epilogue (verified r1-r5): C/D layout col=lane&15, row=quad*4+reg ---
#pragma unroll
  for (int i = 0; i < 4; ++i) {
#pragma unroll
    for (int j = 0; j < 4; ++j) {
      int col = n0 + nw + j * 16 + l16;
      if (col < COLS) {
        int b = col / FRAMES;
        int o = col - b * FRAMES;
        int rowb = m0 + mw + i * 16 + quad * 4;
        float* op = out + (size_t)b * N_ * FRAMES + (size_t)rowb * FRAMES + o;
#pragma unroll
        for (int r = 0; r < 4; ++r) op[(size_t)r * FRAMES] = acc[i][j][r];
      }
    }
  }
}

// ---------------- Fallback: direct fp32 conv (if ws too small) --------------
__global__ void naive_conv(const float* __restrict__ x, const float* __restrict__ f,
                           float* __restrict__ out) {
  int col = blockIdx.x;
  int k = threadIdx.x;
  __shared__ float win[1024];
  int b = col / FRAMES;
  int o = col - b * FRAMES;
  const float* xb = x + (size_t)b * LEN;
  int g = o * N_ - N_;
  for (int t = threadIdx.x; t < 1024; t += 512) {
    int i = g + t;
    win[t] = (i >= 0 && i < LEN) ? xb[i] : 0.0f;
  }
  __syncthreads();
  float s = 0.0f;
  const float* fk = f + (size_t)k * 1024;
  for (int t = 0; t < 1024; ++t) s += win[t] * fk[t];
  out[(size_t)b * N_ * FRAMES + (size_t)k * FRAMES + o] = s;
}

extern "C" void kernel_launch(void* const* d_in, const int* in_sizes, int n_in,
                              void* d_out, int out_size, void* d_ws, size_t ws_size,
                              hipStream_t stream) {
  const float* x = (const float*)d_in[0];
  const float* f = (const float*)d_in[1];
  float* out = (float*)d_out;

  const size_t need = (size_t)512 * 512 * sizeof(_Float16);
  if (ws_size < need) {
    naive_conv<<<COLS, 512, 0, stream>>>(x, f, out);
    return;
  }

  _Float16* D = (_Float16*)d_ws;
  prep_filter<<<256, 256, 0, stream>>>(f, D);
  // Grid 1056 = 132*8: covers nt=0..256, m=0..3 (max id 1048); tail exits.
  gemm_fused<<<1056, 256, 0, stream>>>(D, x, out);
}

// Round 7
// 144.843 us; speedup vs baseline: 1.1455x; 1.1455x over previous
//
#include <hip/hip_runtime.h>
#include <hip/hip_bf16.h>
#include <stdint.h>
#include <stddef.h>

// MDCT as folded GEMM, TWO-KERNEL structure (round-2 verified best) +
// XCD-swizzled gemm grid (round-5 verified: same-n blocks on one XCD).
//   out[512, 32784] = D[512,512] . V[512, 32784]
//   V[c][j] = j<256:  x[g+j] - x[g+511-j]
//             j>=256: x[g+j+256] + x[g+1279-j],   g = o*512 - 512 (per batch)
// Round-6 lessons: (a) fold fused into the GEMM's barrier-locked staging path
// costs more than a separate pass (register vmcnt wait serializes every
// k-iter); (b) BK=32 XOR swizzle only covers 4 bank-groups -> 4-way read
// conflicts. Reverted to BK=64 single-buffer gemm (0 conflicts, 41.5 us).
// Precision: single fp16 product; absmax 0.03125 vs threshold 0.1069.

constexpr int N_ = 512;
constexpr int T_ = 2048;
constexpr int B_ = 16;
constexpr int LEN = N_ * T_;              // 2^20 per batch
constexpr int FRAMES = T_ + 1;            // 2049
constexpr int COLS = B_ * FRAMES;         // 32784
constexpr int NT_TILES = 257;
constexpr int COLS_PAD = NT_TILES * 128;  // 32896
constexpr int KF = 512;
constexpr int BK = 64;

typedef __attribute__((ext_vector_type(8))) _Float16 f16x8;
typedef __attribute__((ext_vector_type(4))) _Float16 f16x4;
typedef __attribute__((ext_vector_type(4))) float f32x4;

#define GLD16(gptr, lptr)                                                     \
  __builtin_amdgcn_global_load_lds(                                           \
      (const __attribute__((address_space(1))) unsigned int*)(gptr),          \
      (__attribute__((address_space(3))) unsigned int*)(lptr), 16, 0, 0)

// ---------------- Kernel 1: gather filter -> fp16 D -------------------------
__global__ void prep_filter(const float* __restrict__ f,
                            _Float16* __restrict__ D) {
  int idx = (blockIdx.x * 256 + threadIdx.x) * 4;
  int k = idx >> 9;
  int j = idx & 511;
  int t = (j < 256) ? j : (j + 256);
  const float4 v = *(const float4*)&f[k * 1024 + t];
  f16x4 h = {(_Float16)v.x, (_Float16)v.y, (_Float16)v.z, (_Float16)v.w};
  *(f16x4*)&D[k * KF + j] = h;
}

// ---------------- Kernel 2: fold x -> V fp16, one wave per column -----------
// Lane l owns V[c][j0..j0+7]: l<32 -> j0=8l (minus half), l>=32 -> j0=256+8(l-32)
// (plus half). fwd stream ascending contiguous, rev stream descending
// contiguous; one f16x8 (16B) store -> wave writes the whole 1KB column.
__global__ void fold_x(const float* __restrict__ x, _Float16* __restrict__ V) {
  const int c = blockIdx.x * 4 + (threadIdx.x >> 6);  // 4 columns per block
  const int l = threadIdx.x & 63;
  const bool mi = (l < 32);
  const int j0 = mi ? (l * 8) : (256 + (l - 32) * 8);
  const float sgn = mi ? -1.0f : 1.0f;
  float4 a0 = {0.f, 0.f, 0.f, 0.f}, a1 = {0.f, 0.f, 0.f, 0.f};
  float4 r0 = {0.f, 0.f, 0.f, 0.f}, r1 = {0.f, 0.f, 0.f, 0.f};
  if (c < COLS) {
    int b = (int)((unsigned)c / (unsigned)FRAMES);
    int o = c - b * FRAMES;
    const int lo = b * LEN;
    const int g = lo + o * N_ - N_;            // absolute window start
    const int fb = g + (mi ? j0 : (j0 + 256)); // fwd segment (8 floats)
    const int rb = g + (mi ? (504 - j0) : (1272 - j0)); // rev segment
    // segments are 8-float aligned; batch bounds are multiples of 512
    // -> each 8-float segment is fully in or fully out (one predicate).
    if ((unsigned)(fb - lo) <= (unsigned)(LEN - 8)) {
      a0 = *(const float4*)(x + fb);
      a1 = *(const float4*)(x + fb + 4);
    }
    if ((unsigned)(rb - lo) <= (unsigned)(LEN - 8)) {
      r0 = *(const float4*)(x + rb);
      r1 = *(const float4*)(x + rb + 4);
    }
  }
  f16x8 h;
  h[0] = (_Float16)__builtin_fmaf(sgn, r1.w, a0.x);
  h[1] = (_Float16)__builtin_fmaf(sgn, r1.z, a0.y);
  h[2] = (_Float16)__builtin_fmaf(sgn, r1.y, a0.z);
  h[3] = (_Float16)__builtin_fmaf(sgn, r1.x, a0.w);
  h[4] = (_Float16)__builtin_fmaf(sgn, r0.w, a1.x);
  h[5] = (_Float16)__builtin_fmaf(sgn, r0.z, a1.y);
  h[6] = (_Float16)__builtin_fmaf(sgn, r0.y, a1.z);
  h[7] = (_Float16)__builtin_fmaf(sgn, r0.x, a1.w);
  if (c < COLS_PAD) *(f16x8*)&V[(size_t)c * KF + j0] = h;
}

// ---------------- Kernel 3: C = D . V, fp16 MFMA (round-2 verified) ---------
// 128x128 tile, BK=64 single-buffer, 4 waves (2x2 of 64x64), 16x16x32 f16.
// LDS slot = r*8 + (chunk ^ (r&7)) -> fragment reads 2-way aliased (free).
// Grid: 1056; id -> xcd=id&7, s=id>>3, m=s&3, nt=(s>>2)*8+xcd (r5 verified:
// FETCH 263->62 MB on the fused variant). Tail nt>=257 exits.
__global__ __launch_bounds__(256, 4) void gemm_fold(
    const _Float16* __restrict__ D, const _Float16* __restrict__ V,
    float* __restrict__ out) {
  __shared__ __align__(16) _Float16 As[128 * BK];
  __shared__ __align__(16) _Float16 Bs[128 * BK];

  const int id = blockIdx.x;
  const int xcd = id & 7;
  const int sb = id >> 3;
  const int nt = (sb >> 2) * 8 + xcd;
  if (nt >= NT_TILES) return;
  const int m0 = (sb & 3) * 128;
  const int n0 = nt * 128;

  const int tid = threadIdx.x;
  const int wid = tid >> 6;
  const int lane = tid & 63;
  const int quad = lane >> 4;
  const int l16 = lane & 15;
  const int mw = (wid >> 1) * 64;
  const int nw = (wid & 1) * 64;

  f32x4 acc[4][4];
#pragma unroll
  for (int i = 0; i < 4; ++i)
#pragma unroll
    for (int j = 0; j < 4; ++j) acc[i][j] = (f32x4){0.f, 0.f, 0.f, 0.f};

  for (int kt = 0; kt < KF / BK; ++kt) {  // 8 iterations
    const int kb = kt * BK;
    __syncthreads();  // previous tile fully consumed
#pragma unroll
    for (int it = 0; it < 4; ++it) {
      const int S = it * 256 + tid;          // LDS slot = uniform base + lane
      const int r = S >> 3;                  // tile row
      const int c = (S & 7) ^ (r & 7);       // swizzled global chunk
      const int goff = kb + c * 8;           // halves
      GLD16(D + (size_t)(m0 + r) * KF + goff, &As[S * 8]);
      GLD16(V + (size_t)(n0 + r) * KF + goff, &Bs[S * 8]);
    }
    __syncthreads();  // drains vmcnt: tiles ready

#pragma unroll
    for (int ko = 0; ko < 2; ++ko) {
      f16x8 af[4], bf[4];
#pragma unroll
      for (int i = 0; i < 4; ++i) {
        int ra = mw + i * 16 + l16;
        int rb = nw + i * 16 + l16;
        int ca = ko * 4 + quad;
        af[i] = *(const f16x8*)&As[(ra * 8 + (ca ^ (ra & 7))) * 8];
        bf[i] = *(const f16x8*)&Bs[(rb * 8 + (ca ^ (rb & 7))) * 8];
      }
#pragma unroll
      for (int i = 0; i < 4; ++i)
#pragma unroll
        for (int j = 0; j < 4; ++j)
          acc[i][j] = __builtin_amdgcn_mfma_f32_16x16x32_f16(af[i], bf[j], acc[i][j], 0, 0, 0);
    }
  }

  // Epilogue (verified r1-r6): C/D layout col = lane&15, row = quad*4 + reg.
#pragma unroll
  for (int i = 0; i < 4; ++i) {
#pragma unroll
    for (int j = 0; j < 4; ++j) {
      int col = n0 + nw + j * 16 + l16;
      if (col < COLS) {
        int b = col / FRAMES;
        int o = col - b * FRAMES;
        int rowb = m0 + mw + i * 16 + quad * 4;
        float* op = out + (size_t)b * N_ * FRAMES + (size_t)rowb * FRAMES + o;
#pragma unroll
        for (int r = 0; r < 4; ++r) op[(size_t)r * FRAMES] = acc[i][j][r];
      }
    }
  }
}

// ---------------- Fallback: direct fp32 conv (if ws too small) --------------
__global__ void naive_conv(const float* __restrict__ x, const float* __restrict__ f,
                           float* __restrict__ out) {
  int col = blockIdx.x;
  int k = threadIdx.x;
  __shared__ float win[1024];
  int b = col / FRAMES;
  int o = col - b * FRAMES;
  const float* xb = x + (size_t)b * LEN;
  int g = o * N_ - N_;
  for (int t = threadIdx.x; t < 1024; t += 512) {
    int i = g + t;
    win[t] = (i >= 0 && i < LEN) ? xb[i] : 0.0f;
  }
  __syncthreads();
  float s = 0.0f;
  const float* fk = f + (size_t)k * 1024;
  for (int t = 0; t < 1024; ++t) s += win[t] * fk[t];
  out[(size_t)b * N_ * FRAMES + (size_t)k * FRAMES + o] = s;
}

extern "C" void kernel_launch(void* const* d_in, const int* in_sizes, int n_in,
                              void* d_out, int out_size, void* d_ws, size_t ws_size,
                              hipStream_t stream) {
  const float* x = (const float*)d_in[0];
  const float* f = (const float*)d_in[1];
  float* out = (float*)d_out;

  const size_t elems_D = (size_t)512 * 512;
  const size_t elems_V = (size_t)COLS_PAD * KF;
  const size_t need = (elems_D + elems_V) * sizeof(_Float16);

  if (ws_size < need) {
    naive_conv<<<COLS, 512, 0, stream>>>(x, f, out);
    return;
  }

  _Float16* D = (_Float16*)d_ws;
  _Float16* V = D + elems_D;

  prep_filter<<<256, 256, 0, stream>>>(f, D);
  fold_x<<<COLS_PAD / 4, 256, 0, stream>>>(x, V);
  // Grid 1056 = 132*8: covers nt=0..256, m=0..3 (max id 1048); tail exits.
  gemm_fold<<<1056, 256, 0, stream>>>(D, V, out);
}